// Round 1
// baseline (157.570 us; speedup 1.0000x reference)
//
#include <hip/hip_runtime.h>

// SAGPool on MI355X: graphs are contiguous 64-node blocks, A is block-diagonal.
// One block per graph; everything in LDS; f32 VALU compute.

#define NGRAPH 128
#define EPG    1024     // edges per graph = NPG*DEG
#define ETOT   131072   // total edges
#define DIM    128      // D_IN = H
#define KSEL   32
#define SA     68       // A row stride (floats), pad for banks, float4-aligned
#define SH     132      // X/H/T row stride (floats), pad for banks, float4-aligned

#define OFF_A   0
#define OFF_W   (64*SA)              // 4352
#define OFF_T   (OFF_W + 16*DIM)     // 6400
#define OFF_H1  (OFF_T  + 64*SH)     // 14848
#define OFF_H2  (OFF_H1 + 64*SH)     // 23296
#define OFF_H3  (OFF_H2 + 64*SH)     // 31744
#define OFF_PRE (OFF_H3 + 64*SH)     // 40192
#define OFF_SC  (OFF_PRE + 64)       // 40256
#define OFF_SEL (OFF_SC + 64)        // 40320
#define LDS_FLOATS (OFF_SEL + 64)    // 40384
#define LDS_BYTES  (LDS_FLOATS * 4)  // 161536  (< 163840)

#define FMA8(A, xs, w0, w1) do { \
  A[0] += (xs)*(w0).x; A[1] += (xs)*(w0).y; A[2] += (xs)*(w0).z; A[3] += (xs)*(w0).w; \
  A[4] += (xs)*(w1).x; A[5] += (xs)*(w1).y; A[6] += (xs)*(w1).z; A[7] += (xs)*(w1).w; } while(0)

// One GCN layer: OUT = relu(A @ (IN @ W) + b); pre[r] += OUT[r,:] . waCol
__device__ __forceinline__ void gcn_layer(float* lds, const float* IN, float* OUT,
                                          const float* __restrict__ Wg,
                                          const float* __restrict__ bg,
                                          const float* __restrict__ waCol, int tid)
{
  float* sW  = lds + OFF_W;
  float* sT  = lds + OFF_T;
  float* sA  = lds + OFF_A;
  float* pre = lds + OFF_PRE;
  const int rq = tid >> 4;   // 0..15 -> 4 rows
  const int cb = tid & 15;   // 0..15 -> 8 cols
  const int r0 = rq * 4;
  const int c0 = cb * 8;

  // ---- phase 1: T = IN @ W  (64x128 = 64x128 @ 128x128) ----
  float acc[4][8];
  #pragma unroll
  for (int rr = 0; rr < 4; ++rr)
    #pragma unroll
    for (int cc = 0; cc < 8; ++cc) acc[rr][cc] = 0.f;

  for (int kc = 0; kc < 8; ++kc) {
    { // stage 16 rows of W into LDS (coalesced)
      const float4* wsrc = (const float4*)(Wg + kc * 16 * DIM);
      float4* wdst = (float4*)sW;
      wdst[tid]       = wsrc[tid];
      wdst[tid + 256] = wsrc[tid + 256];
    }
    __syncthreads();
    #pragma unroll
    for (int kt = 0; kt < 4; ++kt) {
      const int kl = kt * 4;
      const int kg = kc * 16 + kl;
      float4 xv[4];
      #pragma unroll
      for (int rr = 0; rr < 4; ++rr)
        xv[rr] = *(const float4*)&IN[(r0 + rr) * SH + kg];
      float4 w0[4], w1[4];
      #pragma unroll
      for (int i = 0; i < 4; ++i) {
        w0[i] = *(const float4*)&sW[(kl + i) * DIM + c0];
        w1[i] = *(const float4*)&sW[(kl + i) * DIM + c0 + 4];
      }
      #pragma unroll
      for (int rr = 0; rr < 4; ++rr) {
        FMA8(acc[rr], xv[rr].x, w0[0], w1[0]);
        FMA8(acc[rr], xv[rr].y, w0[1], w1[1]);
        FMA8(acc[rr], xv[rr].z, w0[2], w1[2]);
        FMA8(acc[rr], xv[rr].w, w0[3], w1[3]);
      }
    }
    __syncthreads();
  }
  #pragma unroll
  for (int rr = 0; rr < 4; ++rr) {
    float4 t0 = make_float4(acc[rr][0], acc[rr][1], acc[rr][2], acc[rr][3]);
    float4 t1 = make_float4(acc[rr][4], acc[rr][5], acc[rr][6], acc[rr][7]);
    *(float4*)&sT[(r0 + rr) * SH + c0]     = t0;
    *(float4*)&sT[(r0 + rr) * SH + c0 + 4] = t1;
  }
  __syncthreads();

  // ---- phase 2: H = A @ T + b, relu; accumulate attention pre-score ----
  float4 bv0 = *(const float4*)&bg[c0];
  float4 bv1 = *(const float4*)&bg[c0 + 4];
  float a2[4][8];
  #pragma unroll
  for (int rr = 0; rr < 4; ++rr) {
    a2[rr][0] = bv0.x; a2[rr][1] = bv0.y; a2[rr][2] = bv0.z; a2[rr][3] = bv0.w;
    a2[rr][4] = bv1.x; a2[rr][5] = bv1.y; a2[rr][6] = bv1.z; a2[rr][7] = bv1.w;
  }
  for (int j = 0; j < 64; j += 4) {
    float4 av[4];
    #pragma unroll
    for (int rr = 0; rr < 4; ++rr)
      av[rr] = *(const float4*)&sA[(r0 + rr) * SA + j];
    float4 t0[4], t1[4];
    #pragma unroll
    for (int jj = 0; jj < 4; ++jj) {
      t0[jj] = *(const float4*)&sT[(j + jj) * SH + c0];
      t1[jj] = *(const float4*)&sT[(j + jj) * SH + c0 + 4];
    }
    #pragma unroll
    for (int rr = 0; rr < 4; ++rr) {
      FMA8(a2[rr], av[rr].x, t0[0], t1[0]);
      FMA8(a2[rr], av[rr].y, t0[1], t1[1]);
      FMA8(a2[rr], av[rr].z, t0[2], t1[2]);
      FMA8(a2[rr], av[rr].w, t0[3], t1[3]);
    }
  }
  float4 wa0 = *(const float4*)&waCol[c0];
  float4 wa1 = *(const float4*)&waCol[c0 + 4];
  float pp[4];
  #pragma unroll
  for (int rr = 0; rr < 4; ++rr) {
    float4 o0, o1;
    o0.x = fmaxf(a2[rr][0], 0.f); o0.y = fmaxf(a2[rr][1], 0.f);
    o0.z = fmaxf(a2[rr][2], 0.f); o0.w = fmaxf(a2[rr][3], 0.f);
    o1.x = fmaxf(a2[rr][4], 0.f); o1.y = fmaxf(a2[rr][5], 0.f);
    o1.z = fmaxf(a2[rr][6], 0.f); o1.w = fmaxf(a2[rr][7], 0.f);
    *(float4*)&OUT[(r0 + rr) * SH + c0]     = o0;
    *(float4*)&OUT[(r0 + rr) * SH + c0 + 4] = o1;
    pp[rr] = o0.x*wa0.x + o0.y*wa0.y + o0.z*wa0.z + o0.w*wa0.w
           + o1.x*wa1.x + o1.y*wa1.y + o1.z*wa1.z + o1.w*wa1.w;
  }
  #pragma unroll
  for (int rr = 0; rr < 4; ++rr) {
    pp[rr] += __shfl_xor(pp[rr], 1);
    pp[rr] += __shfl_xor(pp[rr], 2);
    pp[rr] += __shfl_xor(pp[rr], 4);
    pp[rr] += __shfl_xor(pp[rr], 8);
  }
  if ((tid & 15) == 0) {
    #pragma unroll
    for (int rr = 0; rr < 4; ++rr) pre[r0 + rr] += pp[rr];
  }
  __syncthreads();
}

extern "C" __global__ void __launch_bounds__(256, 1)
sagpool(const float* __restrict__ x,  const int* __restrict__ ei,
        const float* __restrict__ W1, const float* __restrict__ b1,
        const float* __restrict__ W2, const float* __restrict__ b2,
        const float* __restrict__ W3, const float* __restrict__ b3,
        const float* __restrict__ Wa, const float* __restrict__ ba,
        const float* __restrict__ M1, const float* __restrict__ c1,
        const float* __restrict__ M2, const float* __restrict__ c2,
        const float* __restrict__ M3, const float* __restrict__ c3,
        float* __restrict__ out)
{
  extern __shared__ float lds[];
  const int g   = blockIdx.x;
  const int tid = threadIdx.x;
  float* sA  = lds + OFF_A;
  float* pre = lds + OFF_PRE;
  float* sc  = lds + OFF_SC;
  float* sel = lds + OFF_SEL;

  // ---- build adjacency ----
  for (int i = tid; i < 64 * SA; i += 256) sA[i] = 0.f;
  if (tid < 64) pre[tid] = 0.f;
  __syncthreads();
  {
    const int* srcp = ei + g * EPG;
    const int* dstp = ei + ETOT + g * EPG;
    #pragma unroll
    for (int t = 0; t < 4; ++t) {
      int e = tid + t * 256;
      int s = srcp[e] & 63;
      int d = dstp[e] & 63;
      sA[s * SA + d] = 1.0f;
      sA[d * SA + s] = 1.0f;
    }
  }
  __syncthreads();
  if (tid < 64) sA[tid * SA + tid] += 1.0f;   // + I (self-edge -> 2.0, matches ref)
  __syncthreads();
  { // row sums -> dinv (temp in sc)
    int r = tid >> 2, q = tid & 3;
    float sum = 0.f;
    int jb = q * 16;
    #pragma unroll
    for (int j = 0; j < 16; ++j) sum += sA[r * SA + jb + j];
    sum += __shfl_xor(sum, 1);
    sum += __shfl_xor(sum, 2);
    if (q == 0) sc[r] = 1.0f / sqrtf(sum);
  }
  __syncthreads();
  for (int i = tid; i < 4096; i += 256) {     // A = D^-1/2 (A+I) D^-1/2
    int r = i >> 6, c = i & 63;
    sA[r * SA + c] *= sc[r] * sc[c];
  }
  { // stage x into H3 buffer
    const float4* xg = (const float4*)(x + g * 64 * DIM);
    float* h3 = lds + OFF_H3;
    for (int i = tid; i < 2048; i += 256) {
      int r = i >> 5, c4 = i & 31;
      *(float4*)&h3[r * SH + c4 * 4] = xg[i];
    }
  }
  __syncthreads();

  // ---- 3 GCN layers (h3 buffer is reused for layer-3 output) ----
  gcn_layer(lds, lds + OFF_H3, lds + OFF_H1, W1, b1, Wa + 0,   tid);
  gcn_layer(lds, lds + OFF_H1, lds + OFF_H2, W2, b2, Wa + 128, tid);
  gcn_layer(lds, lds + OFF_H2, lds + OFF_H3, W3, b3, Wa + 256, tid);

  // ---- score = tanh(A @ pre + ba) ----
  {
    int r = tid >> 2, q = tid & 3;
    float partial = 0.f;
    int jb = q * 16;
    #pragma unroll
    for (int j = 0; j < 16; ++j) partial += sA[r * SA + jb + j] * pre[jb + j];
    partial += __shfl_xor(partial, 1);
    partial += __shfl_xor(partial, 2);
    if (q == 0) sc[r] = tanhf(partial + ba[0]);
  }
  __syncthreads();

  // ---- top-K selection by rank (value desc, index asc — lax.top_k ties) ----
  if (tid < 64) {
    float mys = sc[tid];
    int cnt = 0;
    for (int j = 0; j < 64; ++j) {
      float sj = sc[j];
      cnt += (sj > mys || (sj == mys && j < tid)) ? 1 : 0;
    }
    sel[tid] = (cnt < KSEL) ? 1.0f : 0.0f;
  }
  __syncthreads();

  // ---- readout: mean || max of score-masked selected rows (sT is free now) ----
  float* ro  = lds + OFF_T;        // 768
  float* mh  = lds + OFF_T + 768;  // 256
  float* hm  = lds + OFF_T + 1024; // 128
  float* h2m = lds + OFF_T + 1152; // 64
  for (int c = tid; c < 384; c += 256) {
    int which = c >> 7, cc = c & 127;
    const float* buf = (which == 0) ? (lds + OFF_H1)
                     : (which == 1) ? (lds + OFF_H2) : (lds + OFF_H3);
    float sum = 0.f, mx = -1e30f;
    for (int i = 0; i < 64; ++i) {
      if (sel[i] > 0.5f) {
        float v = sc[i] * buf[i * SH + cc];
        sum += v;
        mx = fmaxf(mx, v);
      }
    }
    ro[c]       = sum * (1.0f / KSEL);
    ro[384 + c] = mx;
  }
  __syncthreads();

  // ---- MLP: 768 -> 128 -> 64 -> 10 ----
  {
    int j = tid & 127, half = tid >> 7;
    float acc = 0.f;
    int k0 = half * 384;
    for (int k = k0; k < k0 + 384; k += 4) {
      float4 r4 = *(const float4*)&ro[k];
      acc += r4.x * M1[(k + 0) * DIM + j];
      acc += r4.y * M1[(k + 1) * DIM + j];
      acc += r4.z * M1[(k + 2) * DIM + j];
      acc += r4.w * M1[(k + 3) * DIM + j];
    }
    mh[half * 128 + j] = acc;
  }
  __syncthreads();
  if (tid < 128) hm[tid] = fmaxf(mh[tid] + mh[128 + tid] + c1[tid], 0.f);
  __syncthreads();
  if (tid < 64) {
    float acc = c2[tid];
    for (int k = 0; k < 128; ++k) acc += hm[k] * M2[k * 64 + tid];
    h2m[tid] = fmaxf(acc, 0.f);
  }
  __syncthreads();
  if (tid < 10) {
    float acc = c3[tid];
    for (int k = 0; k < 64; ++k) acc += h2m[k] * M3[k * 10 + tid];
    out[g * 10 + tid] = acc;
  }
}

extern "C" void kernel_launch(void* const* d_in, const int* in_sizes, int n_in,
                              void* d_out, int out_size, void* d_ws, size_t ws_size,
                              hipStream_t stream) {
  const float* x  = (const float*)d_in[0];
  const int*   ei = (const int*)d_in[1];
  // d_in[2] (batch) unused: graphs are contiguous 64-node blocks by construction
  const float* W1 = (const float*)d_in[3];
  const float* b1 = (const float*)d_in[4];
  const float* W2 = (const float*)d_in[5];
  const float* b2 = (const float*)d_in[6];
  const float* W3 = (const float*)d_in[7];
  const float* b3 = (const float*)d_in[8];
  const float* Wa = (const float*)d_in[9];
  const float* ba = (const float*)d_in[10];
  const float* M1 = (const float*)d_in[11];
  const float* c1 = (const float*)d_in[12];
  const float* M2 = (const float*)d_in[13];
  const float* c2 = (const float*)d_in[14];
  const float* M3 = (const float*)d_in[15];
  const float* c3 = (const float*)d_in[16];
  float* out = (float*)d_out;

  (void)hipFuncSetAttribute(reinterpret_cast<const void*>(sagpool),
                            hipFuncAttributeMaxDynamicSharedMemorySize, LDS_BYTES);
  sagpool<<<NGRAPH, 256, LDS_BYTES, stream>>>(x, ei, W1, b1, W2, b2, W3, b3,
                                              Wa, ba, M1, c1, M2, c2, M3, c3, out);
}